// Round 11
// baseline (426.698 us; speedup 1.0000x reference)
//
#include <hip/hip_runtime.h>
#include <hip/hip_cooperative_groups.h>
namespace cg = cooperative_groups;

// ---------- types ----------
typedef __bf16    bf16x4 __attribute__((ext_vector_type(4)));
typedef __bf16    bf16x8 __attribute__((ext_vector_type(8)));
typedef _Float16  f16x2  __attribute__((ext_vector_type(2)));
typedef _Float16  f16x4  __attribute__((ext_vector_type(4)));
typedef float     f32x4  __attribute__((ext_vector_type(4)));

#define MFMA16x16x32 __builtin_amdgcn_mfma_f32_16x16x32_bf16
#define MFMA16x16x16F __builtin_amdgcn_mfma_f32_16x16x16f16

__device__ __forceinline__ void gload_lds16(const void* g, void* l) {
  __builtin_amdgcn_global_load_lds((const __attribute__((address_space(1))) void*)g,
                                   (__attribute__((address_space(3))) void*)l, 16, 0, 0);
}

__device__ __forceinline__ f16x2 pkrtz(float a, float b) {
  return __builtin_bit_cast(f16x2, __builtin_amdgcn_cvt_pkrtz(a, b));
}

// ================= FUSED cooperative kernel: 256 blocks x 512 threads =================
// Each stage processes work items b and b+256. launch_bounds(512,2) => >=1 block/CU
// guaranteed schedulable, so a 256-block cooperative launch cannot be "too large".
__global__ __launch_bounds__(512, 2) void fused_all(
    const float* __restrict__ x, const float* __restrict__ Wqkv,
    const float* __restrict__ bqkv, const float* __restrict__ Wproj,
    const float* __restrict__ bproj,
    __bf16* __restrict__ WvT, __bf16* __restrict__ WpT,
    __bf16* __restrict__ V, _Float16* __restrict__ Vt,
    __bf16* __restrict__ Ob, float* __restrict__ out) {
  __shared__ char lds[65536];
  const int t = threadIdx.x, b = blockIdx.x;
  const int w = t >> 6, l = t & 63, lr = l & 15, quad = l >> 4;
  cg::grid_group grid = cg::this_grid();

  // ======== stage 1: weight transposes (512 tiles, 2/block) ========
  for (int ii = 0; ii < 2; ii++) {
    __syncthreads();
    float* tile = (float*)lds;  // [64][65]
    const float* src; __bf16* dst; int ld, c0;
    if (ii == 0) { src = Wqkv;  dst = WvT; ld = 3072; c0 = 2048; }
    else         { src = Wproj; dst = WpT; ld = 1024; c0 = 0; }
    const int k0 = (b >> 4) * 64, n0 = (b & 15) * 64;
#pragma unroll
    for (int i = 0; i < 2; i++) {
      int idx = t + i * 512; int r = idx >> 4, g = idx & 15;
      float4 v = *(const float4*)&src[(size_t)(k0 + r) * ld + c0 + n0 + g * 4];
      tile[r * 65 + g * 4 + 0] = v.x; tile[r * 65 + g * 4 + 1] = v.y;
      tile[r * 65 + g * 4 + 2] = v.z; tile[r * 65 + g * 4 + 3] = v.w;
    }
    __syncthreads();
#pragma unroll
    for (int i = 0; i < 2; i++) {
      int idx = t + i * 512; int n = idx >> 4, g = idx & 15;
      bf16x4 o;
      o.x = (__bf16)tile[(g * 4 + 0) * 65 + n]; o.y = (__bf16)tile[(g * 4 + 1) * 65 + n];
      o.z = (__bf16)tile[(g * 4 + 2) * 65 + n]; o.w = (__bf16)tile[(g * 4 + 3) * 65 + n];
      *(bf16x4*)&dst[(size_t)(n0 + n) * 1024 + k0 + g * 4] = o;
    }
  }
  __threadfence();
  grid.sync();

  // ======== stage 2: gemm_v, 128x64 tiles (512, 2/block), dual store V + Vt ========
  for (int ii = 0; ii < 2; ii++) {
    __syncthreads();
    const int tau = b + ii * 256;
    const int m0 = (tau >> 4) * 128, n0 = (tau & 15) * 64;
    const int rmA = t >> 3;
    const int kgAs = (t & 7) ^ (rmA & 7);              // source-side XOR swizzle (m104-safe)
    const float* pA0 = x + (size_t)(m0 + rmA) * 1024 + kgAs * 4;
    const float* pA1 = pA0 + (size_t)64 * 1024;
    const __bf16* pB = WvT + (size_t)(n0 + (t >> 2)) * 1024 + (t & 3) * 8;  // t<256 only
    f32x4 acc[4] = {};
    {
      char* buf = lds;
      gload_lds16(pA0, buf + t * 16);
      gload_lds16(pA1, buf + (t + 512) * 16);
      if (t < 256) gload_lds16(pB, buf + 16384 + t * 16);
    }
    const int rr = w * 16 + lr;
    const int ga0 = rr * 8 + ((2 * quad) ^ (rr & 7));
    const int ga1 = rr * 8 + ((2 * quad + 1) ^ (rr & 7));
    for (int it = 0; it < 32; ++it) {
      __syncthreads();
      if (it + 1 < 32) {
        pA0 += 32; pA1 += 32; pB += 32;
        char* buf = lds + ((it + 1) & 1) * 20480;
        gload_lds16(pA0, buf + t * 16);
        gload_lds16(pA1, buf + (t + 512) * 16);
        if (t < 256) gload_lds16(pB, buf + 16384 + t * 16);
      }
      const char* Abuf = lds + (it & 1) * 20480;
      const char* Bbuf = Abuf + 16384;
      f32x4 a0 = *(const f32x4*)(Abuf + ga0 * 16);
      f32x4 a1 = *(const f32x4*)(Abuf + ga1 * 16);
      bf16x8 af;
      af[0] = (__bf16)a0[0]; af[1] = (__bf16)a0[1]; af[2] = (__bf16)a0[2]; af[3] = (__bf16)a0[3];
      af[4] = (__bf16)a1[0]; af[5] = (__bf16)a1[1]; af[6] = (__bf16)a1[2]; af[7] = (__bf16)a1[3];
#pragma unroll
      for (int nc = 0; nc < 4; nc++) {
        bf16x8 bv = *(const bf16x8*)(Bbuf + (nc * 16 + lr) * 64 + quad * 16);
        acc[nc] = MFMA16x16x32(af, bv, acc[nc], 0, 0, 0);
      }
    }
    const int by = tau & 15;
    const int b_ = m0 >> 11;
    const int ntok0 = (m0 & 2047) + w * 16 + quad * 4;
#pragma unroll
    for (int nc = 0; nc < 4; nc++) {
      int gcol = n0 + nc * 16 + lr;
      float bb2 = bqkv[2048 + gcol];
      float v0 = acc[nc][0] + bb2, v1 = acc[nc][1] + bb2;
      float v2 = acc[nc][2] + bb2, v3 = acc[nc][3] + bb2;
#pragma unroll
      for (int r = 0; r < 4; r++) {
        int grow = m0 + w * 16 + quad * 4 + r;
        float vv = (r == 0) ? v0 : (r == 1) ? v1 : (r == 2) ? v2 : v3;
        V[(size_t)grow * 1024 + gcol] = (__bf16)vv;
      }
      f16x2 lo = pkrtz(v0, v1), hi = pkrtz(v2, v3);
      f16x4 pv; pv[0] = lo[0]; pv[1] = lo[1]; pv[2] = hi[0]; pv[3] = hi[1];
      *(f16x4*)&Vt[((size_t)(b_ * 16 + by) * 64 + nc * 16 + lr) * 2048 + ntok0] = pv;
    }
  }
  __threadfence();
  grid.sync();

  // ======== stage 3: attention (512 units, 2/block; same bh pair for L2 reuse) ========
  for (int ii = 0; ii < 2; ii++) {
    __syncthreads();
    const int u = b + ii * 256;
    const int bh = u & 31, bb = bh >> 4, h = bh & 15;
    const int qb = (u >> 5) * 128 + (w & 3) * 16;
    const int part = w >> 2;

    const __bf16* Vbh = V + (size_t)bb * 2048 * 1024 + h * 64;
    const _Float16* Vtbh = Vt + (size_t)bh * 64 * 2048;

    bf16x8 qf[2][2];
#pragma unroll
    for (int sub = 0; sub < 2; sub++)
#pragma unroll
      for (int ks = 0; ks < 2; ks++)
        qf[sub][ks] = *(const bf16x8*)(Vbh + (size_t)(qb + sub * 64 + lr) * 1024 + ks * 32 + quad * 8);

    const int kva = t >> 3, ua = (t & 7) ^ (kva & 7);
    const __bf16* pK0 = Vbh + (size_t)kva * 1024 + ua * 8;
    const __bf16* pK1 = pK0 + (size_t)64 * 1024;
    const int kb_ = t >> 7, d_ = (t >> 1) & 63, qh = (t & 1) ^ ((d_ >> 2) & 1);
    const _Float16* pV0 = Vtbh + (size_t)d_ * 2048 + kb_ * 16 + qh * 8;
    const _Float16* pV1 = pV0 + 64;

    const int koff0 = lr * 128 + ((quad ^ (lr & 7)) * 16);
    const int koff1 = lr * 128 + (((4 + quad) ^ (lr & 7)) * 16);
    const int xq = (quad >> 1) ^ ((lr >> 2) & 1);
    const int voff = lr * 32 + xq * 16 + (quad & 1) * 8;

    f32x4 o[2][4] = {};
    f32x4 l5[2] = {};
    f16x4 ones; ones[0] = ones[1] = ones[2] = ones[3] = (_Float16)1.0f;
    const float Cc = 0.18033688011112042f;
    const float C8 = 11.541560327111707f;

    {
      char* base = lds;
      gload_lds16(pK0, base + t * 16);
      gload_lds16(pV0, base + 8192 + t * 16);
      gload_lds16(pK1, base + 16384 + t * 16);
      gload_lds16(pV1, base + 24576 + t * 16);
    }
    for (int it = 0; it < 16; ++it) {
      __syncthreads();
      if (it + 1 < 16) {
        pK0 += 131072; pK1 += 131072; pV0 += 128; pV1 += 128;
        char* base = lds + ((it + 1) & 1) * 32768;
        gload_lds16(pK0, base + t * 16);
        gload_lds16(pV0, base + 8192 + t * 16);
        gload_lds16(pK1, base + 16384 + t * 16);
        gload_lds16(pV1, base + 24576 + t * 16);
      }
      const char* Kb = lds + (it & 1) * 32768 + part * 16384;
      const char* Vb = Kb + 8192;

      f32x4 s[2][4] = {};
#pragma unroll
      for (int ks = 0; ks < 2; ks++) {
        const int ko = ks ? koff1 : koff0;
#pragma unroll
        for (int rb = 0; rb < 4; rb++) {
          bf16x8 kf = *(const bf16x8*)(Kb + ko + rb * 2048);
          s[0][rb] = MFMA16x16x32(kf, qf[0][ks], s[0][rb], 0, 0, 0);
          s[1][rb] = MFMA16x16x32(kf, qf[1][ks], s[1][rb], 0, 0, 0);
        }
      }

      f16x4 pf[2][4];
#pragma unroll
      for (int sub = 0; sub < 2; sub++)
#pragma unroll
        for (int rb = 0; rb < 4; rb++) {
          float p0 = __builtin_amdgcn_exp2f(s[sub][rb][0] * Cc - C8);
          float p1 = __builtin_amdgcn_exp2f(s[sub][rb][1] * Cc - C8);
          float p2 = __builtin_amdgcn_exp2f(s[sub][rb][2] * Cc - C8);
          float p3 = __builtin_amdgcn_exp2f(s[sub][rb][3] * Cc - C8);
          f16x2 lo = pkrtz(p0, p1);
          f16x2 hi = pkrtz(p2, p3);
          pf[sub][rb][0] = lo[0]; pf[sub][rb][1] = lo[1];
          pf[sub][rb][2] = hi[0]; pf[sub][rb][3] = hi[1];
        }

#pragma unroll
      for (int kb = 0; kb < 4; kb++) {
#pragma unroll
        for (int db = 0; db < 4; db++) {
          f16x4 vf = *(const f16x4*)(Vb + voff + db * 512 + kb * 2048);
          o[0][db] = MFMA16x16x16F(pf[0][kb], vf, o[0][db], 0, 0, 0);
          o[1][db] = MFMA16x16x16F(pf[1][kb], vf, o[1][db], 0, 0, 0);
        }
        l5[0] = MFMA16x16x16F(pf[0][kb], ones, l5[0], 0, 0, 0);
        l5[1] = MFMA16x16x16F(pf[1][kb], ones, l5[1], 0, 0, 0);
      }
    }

    __syncthreads();
    float* xch = (float*)lds;
    if (w >= 4) {
      float* dsto = xch + (w - 4) * 2048;
#pragma unroll
      for (int sub = 0; sub < 2; sub++)
#pragma unroll
        for (int db = 0; db < 4; db++)
          *(f32x4*)&dsto[(sub * 4 + db) * 256 + l * 4] = o[sub][db];
      float* dstl = xch + 8192 + (w - 4) * 512;
      *(f32x4*)&dstl[l * 4] = l5[0];
      *(f32x4*)&dstl[256 + l * 4] = l5[1];
    }
    __syncthreads();
    if (w < 4) {
      const float* srco = xch + w * 2048;
      const float* srcl = xch + 8192 + w * 512;
#pragma unroll
      for (int sub = 0; sub < 2; sub++) {
#pragma unroll
        for (int db = 0; db < 4; db++)
          o[sub][db] += *(const f32x4*)&srco[(sub * 4 + db) * 256 + l * 4];
        l5[sub] += *(const f32x4*)&srcl[sub * 256 + l * 4];
      }
#pragma unroll
      for (int sub = 0; sub < 2; sub++)
#pragma unroll
        for (int r = 0; r < 4; r++) {
          float lv = 1.0f / l5[sub][r];
          int token = bb * 2048 + qb + sub * 64 + quad * 4 + r;
#pragma unroll
          for (int db = 0; db < 4; db++)
            Ob[(size_t)token * 1024 + h * 64 + db * 16 + lr] = (__bf16)(o[sub][db][r] * lv);
        }
    }
  }
  __threadfence();
  grid.sync();

  // ======== stage 4: gemm_proj, 128x64 tiles (512, 2/block), fp32 out ========
  for (int ii = 0; ii < 2; ii++) {
    __syncthreads();
    const int tau = b + ii * 256;
    const int m0 = (tau >> 4) * 128, n0 = (tau & 15) * 64;
    const __bf16* pA = Ob + (size_t)(m0 + (t >> 2)) * 1024 + (t & 3) * 8;
    const __bf16* pB = WpT + (size_t)(n0 + (t >> 2)) * 1024 + (t & 3) * 8;  // t<256 only
    f32x4 acc[4] = {};
    {
      char* buf = lds;
      gload_lds16(pA, buf + t * 16);
      if (t < 256) gload_lds16(pB, buf + 8192 + t * 16);
    }
    const int rr = w * 16 + lr;
    for (int it = 0; it < 32; ++it) {
      __syncthreads();
      if (it + 1 < 32) {
        pA += 32; pB += 32;
        char* buf = lds + ((it + 1) & 1) * 12288;
        gload_lds16(pA, buf + t * 16);
        if (t < 256) gload_lds16(pB, buf + 8192 + t * 16);
      }
      const char* Abuf = lds + (it & 1) * 12288;
      const char* Bbuf = Abuf + 8192;
      bf16x8 af = *(const bf16x8*)(Abuf + rr * 64 + quad * 16);
#pragma unroll
      for (int nc = 0; nc < 4; nc++) {
        bf16x8 bv = *(const bf16x8*)(Bbuf + (nc * 16 + lr) * 64 + quad * 16);
        acc[nc] = MFMA16x16x32(af, bv, acc[nc], 0, 0, 0);
      }
    }
#pragma unroll
    for (int nc = 0; nc < 4; nc++)
#pragma unroll
      for (int r = 0; r < 4; r++) {
        int grow = m0 + w * 16 + quad * 4 + r;
        int gcol = n0 + nc * 16 + lr;
        out[(size_t)grow * 1024 + gcol] = acc[nc][r] + bproj[gcol];
      }
  }
}

// ================= FALLBACK kernels (r9, verified) =================
__global__ __launch_bounds__(256) void prep_transpose(const float* __restrict__ Wqkv,
                                                      const float* __restrict__ Wproj,
                                                      __bf16* __restrict__ WvT,
                                                      __bf16* __restrict__ WpT) {
  __shared__ float tile[64][65];
  const float* src; __bf16* dst; int ld, c0;
  if (blockIdx.z == 0) { src = Wqkv; dst = WvT; ld = 3072; c0 = 2048; }
  else                 { src = Wproj; dst = WpT; ld = 1024; c0 = 0; }
  const int k0 = blockIdx.x * 64, n0 = blockIdx.y * 64;
  const int t = threadIdx.x;
#pragma unroll
  for (int i = 0; i < 4; i++) {
    int idx = t + i * 256; int r = idx >> 4, g = idx & 15;
    float4 v = *(const float4*)&src[(size_t)(k0 + r) * ld + c0 + n0 + g * 4];
    tile[r][g * 4 + 0] = v.x; tile[r][g * 4 + 1] = v.y;
    tile[r][g * 4 + 2] = v.z; tile[r][g * 4 + 3] = v.w;
  }
  __syncthreads();
#pragma unroll
  for (int i = 0; i < 4; i++) {
    int idx = t + i * 256; int n = idx >> 4, g = idx & 15;
    bf16x4 o;
    o.x = (__bf16)tile[g * 4 + 0][n]; o.y = (__bf16)tile[g * 4 + 1][n];
    o.z = (__bf16)tile[g * 4 + 2][n]; o.w = (__bf16)tile[g * 4 + 3][n];
    *(bf16x4*)&dst[(size_t)(n0 + n) * 1024 + k0 + g * 4] = o;
  }
}

__global__ __launch_bounds__(256, 4) void gemm_v(const float* __restrict__ x,
                                                 const __bf16* __restrict__ WvT,
                                                 const float* __restrict__ bias,
                                                 __bf16* __restrict__ V,
                                                 _Float16* __restrict__ Vt) {
  constexpr int K = 1024;
  __shared__ char lds[2 * 12288];
  const int t = threadIdx.x, w = t >> 6, l = t & 63, lr = l & 15, quad = l >> 4;
  const int m0 = blockIdx.x * 64, n0 = blockIdx.y * 64;
  const int rmA = t >> 3;
  const int kgAs = (t & 7) ^ (rmA & 7);
  const float* pA0 = x + (size_t)(m0 + rmA) * K + kgAs * 4;
  const float* pA1 = pA0 + (size_t)32 * K;
  const int rnB = t >> 2, kgB = t & 3;
  const __bf16* pB = WvT + (size_t)(n0 + rnB) * K + kgB * 8;

  f32x4 acc[4] = {};
  {
    char* buf = (char*)lds;
    gload_lds16(pA0, buf + t * 16);
    gload_lds16(pA1, buf + (t + 256) * 16);
    gload_lds16(pB, buf + 8192 + t * 16);
  }
  const int rr = w * 16 + lr;
  const int ga0 = rr * 8 + ((2 * quad) ^ (rr & 7));
  const int ga1 = rr * 8 + ((2 * quad + 1) ^ (rr & 7));
  for (int it = 0; it < 32; ++it) {
    __syncthreads();
    if (it + 1 < 32) {
      pA0 += 32; pA1 += 32; pB += 32;
      char* buf = (char*)lds + ((it + 1) & 1) * 12288;
      gload_lds16(pA0, buf + t * 16);
      gload_lds16(pA1, buf + (t + 256) * 16);
      gload_lds16(pB, buf + 8192 + t * 16);
    }
    const char* Abuf = (char*)lds + (it & 1) * 12288;
    const char* Bbuf = Abuf + 8192;
    f32x4 a0 = *(const f32x4*)(Abuf + ga0 * 16);
    f32x4 a1 = *(const f32x4*)(Abuf + ga1 * 16);
    bf16x8 af;
    af[0] = (__bf16)a0[0]; af[1] = (__bf16)a0[1]; af[2] = (__bf16)a0[2]; af[3] = (__bf16)a0[3];
    af[4] = (__bf16)a1[0]; af[5] = (__bf16)a1[1]; af[6] = (__bf16)a1[2]; af[7] = (__bf16)a1[3];
#pragma unroll
    for (int nc = 0; nc < 4; nc++) {
      bf16x8 bv = *(const bf16x8*)(Bbuf + (nc * 16 + lr) * 64 + quad * 16);
      acc[nc] = MFMA16x16x32(af, bv, acc[nc], 0, 0, 0);
    }
  }
  const int b_ = blockIdx.x >> 5, by = blockIdx.y;
  const int ntok0 = (m0 & 2047) + w * 16 + quad * 4;
#pragma unroll
  for (int nc = 0; nc < 4; nc++) {
    int gcol = n0 + nc * 16 + lr;
    float bb = bias[gcol];
    float v0 = acc[nc][0] + bb, v1 = acc[nc][1] + bb;
    float v2 = acc[nc][2] + bb, v3 = acc[nc][3] + bb;
#pragma unroll
    for (int r = 0; r < 4; r++) {
      int grow = m0 + w * 16 + quad * 4 + r;
      float vv = (r == 0) ? v0 : (r == 1) ? v1 : (r == 2) ? v2 : v3;
      V[(size_t)grow * 1024 + gcol] = (__bf16)vv;
    }
    f16x2 lo = pkrtz(v0, v1), hi = pkrtz(v2, v3);
    f16x4 pv; pv[0] = lo[0]; pv[1] = lo[1]; pv[2] = hi[0]; pv[3] = hi[1];
    *(f16x4*)&Vt[((size_t)(b_ * 16 + by) * 64 + nc * 16 + lr) * 2048 + ntok0] = pv;
  }
}

__global__ __launch_bounds__(256, 4) void gemm_proj(const __bf16* __restrict__ A,
                                                    const __bf16* __restrict__ Bt,
                                                    const float* __restrict__ bias,
                                                    float* __restrict__ outp) {
  constexpr int K = 1024, Nn = 1024;
  __shared__ __bf16 lds[2 * 4096];
  const int t = threadIdx.x, w = t >> 6, l = t & 63, lr = l & 15, quad = l >> 4;
  const int m0 = blockIdx.x * 64, n0 = blockIdx.y * 64;
  const int rm = t >> 2, kg = t & 3;
  const __bf16* pA = A  + (size_t)(m0 + rm) * K + kg * 8;
  const __bf16* pB = Bt + (size_t)(n0 + rm) * K + kg * 8;
  f32x4 acc[4] = {};
  gload_lds16(pA, (char*)lds + t * 16);
  gload_lds16(pB, (char*)lds + 4096 + t * 16);
  for (int it = 0; it < 32; ++it) {
    __syncthreads();
    if (it + 1 < 32) {
      pA += 32; pB += 32;
      char* buf = (char*)lds + ((it + 1) & 1) * 8192;
      gload_lds16(pA, buf + t * 16);
      gload_lds16(pB, buf + 4096 + t * 16);
    }
    const __bf16* Al = lds + (it & 1) * 4096;
    const __bf16* Bl = Al + 2048;
    bf16x8 af = *(const bf16x8*)&Al[(w * 16 + lr) * 32 + quad * 8];
#pragma unroll
    for (int nc = 0; nc < 4; nc++) {
      bf16x8 bv = *(const bf16x8*)&Bl[(nc * 16 + lr) * 32 + quad * 8];
      acc[nc] = MFMA16x16x32(af, bv, acc[nc], 0, 0, 0);
    }
  }
#pragma unroll
  for (int nc = 0; nc < 4; nc++)
#pragma unroll
    for (int r = 0; r < 4; r++) {
      int grow = m0 + w * 16 + quad * 4 + r;
      int gcol = n0 + nc * 16 + lr;
      outp[(size_t)grow * Nn + gcol] = acc[nc][r] + bias[gcol];
    }
}

__global__ __launch_bounds__(512, 4) void attn_kernel(const __bf16* __restrict__ V,
                                                      const _Float16* __restrict__ Vt,
                                                      __bf16* __restrict__ O) {
  __shared__ char lds[65536];
  const int t = threadIdx.x, w = t >> 6, l = t & 63, lr = l & 15, quad = l >> 4;
  const int bh = blockIdx.x, b = bh >> 4, h = bh & 15;
  const int qb = blockIdx.y * 128 + (w & 3) * 16;
  const int part = w >> 2;
  const __bf16* Vbh = V + (size_t)b * 2048 * 1024 + h * 64;
  const _Float16* Vtbh = Vt + (size_t)bh * 64 * 2048;
  bf16x8 qf[2][2];
#pragma unroll
  for (int sub = 0; sub < 2; sub++)
#pragma unroll
    for (int ks = 0; ks < 2; ks++)
      qf[sub][ks] = *(const bf16x8*)(Vbh + (size_t)(qb + sub * 64 + lr) * 1024 + ks * 32 + quad * 8);
  const int kva = t >> 3, ua = (t & 7) ^ (kva & 7);
  const __bf16* pK0 = Vbh + (size_t)kva * 1024 + ua * 8;
  const __bf16* pK1 = pK0 + (size_t)64 * 1024;
  const int kb_ = t >> 7, d_ = (t >> 1) & 63, qh = (t & 1) ^ ((d_ >> 2) & 1);
  const _Float16* pV0 = Vtbh + (size_t)d_ * 2048 + kb_ * 16 + qh * 8;
  const _Float16* pV1 = pV0 + 64;
  const int koff0 = lr * 128 + ((quad ^ (lr & 7)) * 16);
  const int koff1 = lr * 128 + (((4 + quad) ^ (lr & 7)) * 16);
  const int xq = (quad >> 1) ^ ((lr >> 2) & 1);
  const int voff = lr * 32 + xq * 16 + (quad & 1) * 8;
  f32x4 o[2][4] = {};
  f32x4 l5[2] = {};
  f16x4 ones; ones[0] = ones[1] = ones[2] = ones[3] = (_Float16)1.0f;
  const float Cc = 0.18033688011112042f;
  const float C8 = 11.541560327111707f;
  {
    char* base = lds;
    gload_lds16(pK0, base + t * 16);
    gload_lds16(pV0, base + 8192 + t * 16);
    gload_lds16(pK1, base + 16384 + t * 16);
    gload_lds16(pV1, base + 24576 + t * 16);
  }
  for (int it = 0; it < 16; ++it) {
    __syncthreads();
    if (it + 1 < 16) {
      pK0 += 131072; pK1 += 131072; pV0 += 128; pV1 += 128;
      char* base = lds + ((it + 1) & 1) * 32768;
      gload_lds16(pK0, base + t * 16);
      gload_lds16(pV0, base + 8192 + t * 16);
      gload_lds16(pK1, base + 16384 + t * 16);
      gload_lds16(pV1, base + 24576 + t * 16);
    }
    const char* Kb = lds + (it & 1) * 32768 + part * 16384;
    const char* Vb = Kb + 8192;
    f32x4 s[2][4] = {};
#pragma unroll
    for (int ks = 0; ks < 2; ks++) {
      const int ko = ks ? koff1 : koff0;
#pragma unroll
      for (int rb = 0; rb < 4; rb++) {
        bf16x8 kf = *(const bf16x8*)(Kb + ko + rb * 2048);
        s[0][rb] = MFMA16x16x32(kf, qf[0][ks], s[0][rb], 0, 0, 0);
        s[1][rb] = MFMA16x16x32(kf, qf[1][ks], s[1][rb], 0, 0, 0);
      }
    }
    f16x4 pf[2][4];
#pragma unroll
    for (int sub = 0; sub < 2; sub++)
#pragma unroll
      for (int rb = 0; rb < 4; rb++) {
        float p0 = __builtin_amdgcn_exp2f(s[sub][rb][0] * Cc - C8);
        float p1 = __builtin_amdgcn_exp2f(s[sub][rb][1] * Cc - C8);
        float p2 = __builtin_amdgcn_exp2f(s[sub][rb][2] * Cc - C8);
        float p3 = __builtin_amdgcn_exp2f(s[sub][rb][3] * Cc - C8);
        f16x2 lo = pkrtz(p0, p1);
        f16x2 hi = pkrtz(p2, p3);
        pf[sub][rb][0] = lo[0]; pf[sub][rb][1] = lo[1];
        pf[sub][rb][2] = hi[0]; pf[sub][rb][3] = hi[1];
      }
#pragma unroll
    for (int kb = 0; kb < 4; kb++) {
#pragma unroll
      for (int db = 0; db < 4; db++) {
        f16x4 vf = *(const f16x4*)(Vb + voff + db * 512 + kb * 2048);
        o[0][db] = MFMA16x16x16F(pf[0][kb], vf, o[0][db], 0, 0, 0);
        o[1][db] = MFMA16x16x16F(pf[1][kb], vf, o[1][db], 0, 0, 0);
      }
      l5[0] = MFMA16x16x16F(pf[0][kb], ones, l5[0], 0, 0, 0);
      l5[1] = MFMA16x16x16F(pf[1][kb], ones, l5[1], 0, 0, 0);
    }
  }
  __syncthreads();
  float* xch = (float*)lds;
  if (w >= 4) {
    float* dsto = xch + (w - 4) * 2048;
#pragma unroll
    for (int sub = 0; sub < 2; sub++)
#pragma unroll
      for (int db = 0; db < 4; db++)
        *(f32x4*)&dsto[(sub * 4 + db) * 256 + l * 4] = o[sub][db];
    float* dstl = xch + 8192 + (w - 4) * 512;
    *(f32x4*)&dstl[l * 4] = l5[0];
    *(f32x4*)&dstl[256 + l * 4] = l5[1];
  }
  __syncthreads();
  if (w < 4) {
    const float* srco = xch + w * 2048;
    const float* srcl = xch + 8192 + w * 512;
#pragma unroll
    for (int sub = 0; sub < 2; sub++) {
#pragma unroll
      for (int db = 0; db < 4; db++)
        o[sub][db] += *(const f32x4*)&srco[(sub * 4 + db) * 256 + l * 4];
      l5[sub] += *(const f32x4*)&srcl[sub * 256 + l * 4];
    }
#pragma unroll
    for (int sub = 0; sub < 2; sub++)
#pragma unroll
      for (int r = 0; r < 4; r++) {
        float lv = 1.0f / l5[sub][r];
        int token = b * 2048 + qb + sub * 64 + quad * 4 + r;
#pragma unroll
        for (int db = 0; db < 4; db++)
          O[(size_t)token * 1024 + h * 64 + db * 16 + lr] = (__bf16)(o[sub][db][r] * lv);
      }
  }
}

// ---------- launch: try fused cooperative; on ANY error, fall back to 4-kernel path ----------
extern "C" void kernel_launch(void* const* d_in, const int* in_sizes, int n_in,
                              void* d_out, int out_size, void* d_ws, size_t ws_size,
                              hipStream_t stream) {
  (void)in_sizes; (void)n_in; (void)out_size; (void)ws_size;
  const float* x     = (const float*)d_in[0];
  const float* Wqkv  = (const float*)d_in[1];
  const float* bqkv  = (const float*)d_in[2];
  const float* Wproj = (const float*)d_in[3];
  const float* bproj = (const float*)d_in[4];

  char* ws = (char*)d_ws;
  __bf16*    V   = (__bf16*)(ws);                          // 8 MB  [4096][1024]
  _Float16*  Vt  = (_Float16*)(ws + (size_t)8  * 1048576); // 8 MB  [32][64][2048] f16
  __bf16*    Ob  = (__bf16*)(ws + (size_t)16 * 1048576);   // 8 MB  [4096][1024]
  __bf16*    WvT = (__bf16*)(ws + (size_t)24 * 1048576);   // 2 MB  [1024][1024]
  __bf16*    WpT = (__bf16*)(ws + (size_t)26 * 1048576);   // 2 MB  [1024][1024]
  float*     out = (float*)d_out;

  void* args[] = {&x, &Wqkv, &bqkv, &Wproj, &bproj, &WvT, &WpT, &V, &Vt, &Ob, &out};
  hipError_t err = hipLaunchCooperativeKernel((void*)fused_all, dim3(256), dim3(512),
                                              args, 0, stream);
  if (err != hipSuccess) {
    (void)hipGetLastError();  // clear error state
    prep_transpose<<<dim3(16, 16, 2), 256, 0, stream>>>(Wqkv, Wproj, WvT, WpT);
    gemm_v<<<dim3(64, 16), 256, 0, stream>>>(x, WvT, bqkv + 2048, V, Vt);
    attn_kernel<<<dim3(32, 16), 512, 0, stream>>>(V, Vt, Ob);
    gemm_proj<<<dim3(64, 16), 256, 0, stream>>>(Ob, WpT, bproj, out);
  }
}